// Round 4
// baseline (223.265 us; speedup 1.0000x reference)
//
#include <hip/hip_runtime.h>

// Native 4-float vector (clang ext_vector_type) — required for
// __builtin_nontemporal_load/store (HIP's float4 class is rejected).
typedef float nfloat4 __attribute__((ext_vector_type(4)));

// TWO slices (32x32 fp32 each) per 64-lane wave, branchless sel handling.
// Block = 256 threads = 4 waves = 8 slices; no LDS, no block sync.
// 8 outstanding 16B/lane nontemporal loads per wave; the two argmax chains
// and the two 6-step shuffle butterflies are interleaved so DS-pipe latency
// of slice A overlaps compute of slice B.
__global__ __launch_bounds__(256) void drop_block_kernel(
    const float* __restrict__ x,
    const int* __restrict__ T,
    const int* __restrict__ dropb,
    float* __restrict__ out,
    int n_slices) {
  const int wave = threadIdx.x >> 6;
  const int lane = threadIdx.x & 63;
  const int s0 = blockIdx.x * 8 + wave * 2;
  if (s0 >= n_slices) return;
  const bool has_b = (s0 + 1) < n_slices;

  const nfloat4* __restrict__ xa = (const nfloat4*)x + (size_t)s0 * 256;
  nfloat4* __restrict__ oa = (nfloat4*)out + (size_t)s0 * 256;
  const nfloat4* __restrict__ xb = xa + 256;
  nfloat4* __restrict__ ob = oa + 256;

  // ---- loads: 8 in flight (slice A + slice B)
  nfloat4 a0 = __builtin_nontemporal_load(&xa[lane]);
  nfloat4 a1 = __builtin_nontemporal_load(&xa[lane + 64]);
  nfloat4 a2 = __builtin_nontemporal_load(&xa[lane + 128]);
  nfloat4 a3 = __builtin_nontemporal_load(&xa[lane + 192]);
  nfloat4 b0, b1, b2, b3;
  if (has_b) {
    b0 = __builtin_nontemporal_load(&xb[lane]);
    b1 = __builtin_nontemporal_load(&xb[lane + 64]);
    b2 = __builtin_nontemporal_load(&xb[lane + 128]);
    b3 = __builtin_nontemporal_load(&xb[lane + 192]);
  } else {
    b0 = a0; b1 = a1; b2 = a2; b3 = a3;  // dummy, never stored
  }

  int sel_a = __builtin_amdgcn_readfirstlane(T[s0]);
  int sel_b = has_b ? __builtin_amdgcn_readfirstlane(T[s0 + 1]) : 0;
  const int half = __builtin_amdgcn_readfirstlane(dropb[0]) >> 1;

  // ---- in-lane argmax, 4 independent chunk chains per slice, ordered merge.
  // Strict '>' with ascending-index evaluation => first occurrence wins.
#define ARG4(vec, base, BV, BI)                         \
  float BV = vec.x; int BI = (base);                    \
  if (vec.y > BV) { BV = vec.y; BI = (base) + 1; }      \
  if (vec.z > BV) { BV = vec.z; BI = (base) + 2; }      \
  if (vec.w > BV) { BV = vec.w; BI = (base) + 3; }

  ARG4(a0, lane * 4, av0, ai0)
  ARG4(a1, (lane + 64) * 4, av1, ai1)
  ARG4(a2, (lane + 128) * 4, av2, ai2)
  ARG4(a3, (lane + 192) * 4, av3, ai3)
  ARG4(b0, lane * 4, bv0, bi0)
  ARG4(b1, (lane + 64) * 4, bv1, bi1)
  ARG4(b2, (lane + 128) * 4, bv2, bi2)
  ARG4(b3, (lane + 192) * 4, bv3, bi3)
#undef ARG4

  float av = av0; int ai = ai0;
  if (av1 > av) { av = av1; ai = ai1; }
  if (av2 > av) { av = av2; ai = ai2; }
  if (av3 > av) { av = av3; ai = ai3; }
  float bv = bv0; int bi = bi0;
  if (bv1 > bv) { bv = bv1; bi = bi1; }
  if (bv2 > bv) { bv = bv2; bi = bi2; }
  if (bv3 > bv) { bv = bv3; bi = bi3; }

  // ---- two interleaved 64-wide butterflies, lowest-index tiebreak
  for (int off = 32; off > 0; off >>= 1) {
    float oav = __shfl_xor(av, off, 64);
    int oai = __shfl_xor(ai, off, 64);
    float obv = __shfl_xor(bv, off, 64);
    int obi = __shfl_xor(bi, off, 64);
    if (oav > av || (oav == av && oai < ai)) { av = oav; ai = oai; }
    if (obv > bv || (obv == bv && obi < bi)) { bv = obv; bi = obi; }
  }

  // ---- boxes + normalization (branchless sel: empty box + lam=1)
#define BOX(BI, SEL, H1, H2, W1, W2, LAM)                              \
  int H1, H2, W1, W2; float LAM;                                       \
  {                                                                    \
    const int mh = (BI) >> 5, mw = (BI) & 31;                          \
    int h1 = mh - half; h1 = h1 < 0 ? 0 : (h1 > 31 ? 31 : h1);         \
    int h2 = mh + half; h2 = h2 < 0 ? 0 : (h2 > 31 ? 31 : h2);         \
    int w1 = mw - half; w1 = w1 < 0 ? 0 : (w1 > 31 ? 31 : w1);         \
    int w2 = mw + half; w2 = w2 < 0 ? 0 : (w2 > 31 ? 31 : w2);         \
    const int area = (h2 - h1 + 1) * (w2 - w1 + 1);                    \
    float lam = 1024.0f / (float)(1024 - area);                        \
    H1 = (SEL) ? h1 : 32; /* empty box when sel==0 */                  \
    H2 = h2; W1 = w1; W2 = w2;                                         \
    LAM = (SEL) ? lam : 1.0f;                                          \
  }

  BOX(ai, sel_a, ah1, ah2, aw1, aw2, alam)
  BOX(bi, sel_b, bh1, bh2, bw1, bw2, blam)
#undef BOX

  // ---- apply mask + scale, store (nontemporal)
#define APPLY(vec, base, H1, H2, W1, W2, LAM, optr)                    \
  do {                                                                 \
    nfloat4 _r;                                                        \
    int _i = (base);                                                   \
    int _r0 = _i >> 5, _c0 = _i & 31;                                  \
    bool _in = (_r0 >= H1) & (_r0 <= H2) & (_c0 >= W1) & (_c0 <= W2);  \
    _r.x = _in ? 0.0f : vec.x * LAM;                                   \
    _r0 = (_i + 1) >> 5; _c0 = (_i + 1) & 31;                          \
    _in = (_r0 >= H1) & (_r0 <= H2) & (_c0 >= W1) & (_c0 <= W2);       \
    _r.y = _in ? 0.0f : vec.y * LAM;                                   \
    _r0 = (_i + 2) >> 5; _c0 = (_i + 2) & 31;                          \
    _in = (_r0 >= H1) & (_r0 <= H2) & (_c0 >= W1) & (_c0 <= W2);       \
    _r.z = _in ? 0.0f : vec.z * LAM;                                   \
    _r0 = (_i + 3) >> 5; _c0 = (_i + 3) & 31;                          \
    _in = (_r0 >= H1) & (_r0 <= H2) & (_c0 >= W1) & (_c0 <= W2);       \
    _r.w = _in ? 0.0f : vec.w * LAM;                                   \
    __builtin_nontemporal_store(_r, &(optr)[(base) >> 2]);             \
  } while (0)

  APPLY(a0, lane * 4, ah1, ah2, aw1, aw2, alam, oa);
  APPLY(a1, (lane + 64) * 4, ah1, ah2, aw1, aw2, alam, oa);
  APPLY(a2, (lane + 128) * 4, ah1, ah2, aw1, aw2, alam, oa);
  APPLY(a3, (lane + 192) * 4, ah1, ah2, aw1, aw2, alam, oa);
  if (has_b) {
    APPLY(b0, lane * 4, bh1, bh2, bw1, bw2, blam, ob);
    APPLY(b1, (lane + 64) * 4, bh1, bh2, bw1, bw2, blam, ob);
    APPLY(b2, (lane + 128) * 4, bh1, bh2, bw1, bw2, blam, ob);
    APPLY(b3, (lane + 192) * 4, bh1, bh2, bw1, bw2, blam, ob);
  }
#undef APPLY
}

extern "C" void kernel_launch(void* const* d_in, const int* in_sizes, int n_in,
                              void* d_out, int out_size, void* d_ws, size_t ws_size,
                              hipStream_t stream) {
  const float* x = (const float*)d_in[0];
  const int* T = (const int*)d_in[1];
  const int* dropb = (const int*)d_in[2];
  float* out = (float*)d_out;

  const int n_slices = in_sizes[1];  // 128*256 = 32768
  const int blocks = (n_slices + 7) / 8;  // 8 slices per 256-thread block
  drop_block_kernel<<<blocks, 256, 0, stream>>>(x, T, dropb, out, n_slices);
}